// Round 1
// baseline (250.855 us; speedup 1.0000x reference)
//
#include <hip/hip_runtime.h>
#include <hip/hip_fp16.h>
#include <cstdint>

// Problem shape
#define B_   256
#define CIN  3
#define HW_  64
#define COUT 64
#define FIN  65536   // 64*32*32
#define FOUT 256

// Workspace layout (float indices)
#define ACC_F    0        // 65536 floats: split-K GEMM accumulator
#define SC_F     65536    // [0] maxabs_x bits, [1] max_h bits, [2] p_sf
#define WSF2_F   65552    // 256: per-row absmax bits (uint) of dense_w
#define CBSF_F   65808    // 64: conv bias_sf
#define CBINT_F  65872    // 64: conv b_int (float-valued)
#define CWINT_F  65936    // 1728: conv w_int (float-valued)
#define H16_BYTE (512*1024)  // f16 h buffer, 33.5 MB

typedef _Float16 half8  __attribute__((ext_vector_type(8)));
typedef _Float16 half4v __attribute__((ext_vector_type(4)));
typedef float    floatx4 __attribute__((ext_vector_type(4)));
typedef unsigned short u16;

__device__ inline float blockMax(float v) {
    #pragma unroll
    for (int off = 32; off; off >>= 1) v = fmaxf(v, __shfl_down(v, off));
    __shared__ float sm[8];
    const int lane = threadIdx.x & 63, w = threadIdx.x >> 6;
    if (lane == 0) sm[w] = v;
    __syncthreads();
    float m = sm[0];
    const int nw = blockDim.x >> 6;
    for (int i = 1; i < nw; i++) m = fmaxf(m, sm[i]);
    return m;
}

// ---- kernel 1: global absmax of x ----
__global__ void k_amax_x(const float* __restrict__ x, unsigned* __restrict__ tgt, int n4) {
    const float4* x4 = (const float4*)x;
    float m = 0.f;
    for (int i = blockIdx.x * blockDim.x + threadIdx.x; i < n4; i += gridDim.x * blockDim.x) {
        float4 v = x4[i];
        m = fmaxf(m, fmaxf(fmaxf(fabsf(v.x), fabsf(v.y)), fmaxf(fabsf(v.z), fabsf(v.w))));
    }
    float bm = blockMax(m);
    if (threadIdx.x == 0) atomicMax(tgt, __float_as_uint(bm));
}

// ---- kernel 2: per-row absmax of dense_w (4 blocks per row) ----
__global__ void k_wamax(const float* __restrict__ dw, unsigned* __restrict__ wabs) {
    const int row = blockIdx.x >> 2;
    const int q   = blockIdx.x & 3;
    const float4* r = (const float4*)(dw + (size_t)row * FIN) + q * 4096;
    float m = 0.f;
    for (int i = threadIdx.x; i < 4096; i += 256) {
        float4 v = r[i];
        m = fmaxf(m, fmaxf(fmaxf(fabsf(v.x), fabsf(v.y)), fmaxf(fabsf(v.z), fabsf(v.w))));
    }
    float bm = blockMax(m);
    if (threadIdx.x == 0) atomicMax(wabs + row, __float_as_uint(bm));
}

// ---- kernel 3: quantize conv weights, compute p_sf / bias scales ----
__global__ void k_qconvw(const float* __restrict__ cw, const float* __restrict__ cb,
                         float* ws) {
    const int o = threadIdx.x;  // 64 threads
    const float maxx = __uint_as_float(((const unsigned*)ws)[SC_F + 0]);
    const float p_sf = fmaxf(maxx, 1e-8f) / 32767.0f;
    if (o == 0) ws[SC_F + 2] = p_sf;
    float wv[27];
    float m = 0.f;
    #pragma unroll
    for (int i = 0; i < 27; i++) { wv[i] = cw[o * 27 + i]; m = fmaxf(m, fabsf(wv[i])); }
    const float sf = fmaxf(m, 1e-8f) / 127.0f;
    #pragma unroll
    for (int i = 0; i < 27; i++) {
        float qv = fminf(127.f, fmaxf(-127.f, rintf(wv[i] / sf)));
        ws[CWINT_F + o * 27 + i] = qv;
    }
    const float bsf = p_sf * sf;
    ws[CBSF_F + o]  = bsf;
    ws[CBINT_F + o] = rintf(cb[o] / bsf);
}

// ---- kernel 4: conv 3x3 s2 p1, relu, f16 store, global max(h) ----
// block = (b, oy-tile of 4 rows); thread bits: [4:0]=ox [5]=oy0 [6]=co-half [7]=oy1
// w stays wave-uniform -> scalar loads -> 1 v_fmac per MAC.
__global__ __launch_bounds__(256) void k_conv(const float* __restrict__ x,
                                              const float* __restrict__ ws,
                                              u16* __restrict__ h16,
                                              unsigned* __restrict__ maxh) {
    const int b   = blockIdx.x >> 3;
    const int oyt = (blockIdx.x & 7) * 4;
    const int t   = threadIdx.x;
    const int ox  = t & 31;
    const int ch  = __builtin_amdgcn_readfirstlane((t >> 6) & 1);  // wave-uniform
    const int oy  = oyt + ((t >> 7) << 1) + ((t >> 5) & 1);
    const float p_sf  = ws[SC_F + 2];
    const float inv_p = 1.0f / p_sf;
    const float* xb = x + (size_t)b * (CIN * HW_ * HW_);

    float xs[27];
    #pragma unroll
    for (int ci = 0; ci < 3; ci++)
        #pragma unroll
        for (int ky = 0; ky < 3; ky++) {
            const int iy = 2 * oy - 1 + ky;
            const bool yok = ((unsigned)iy < 64u);
            #pragma unroll
            for (int kx = 0; kx < 3; kx++) {
                const int ix = 2 * ox - 1 + kx;
                float v = (yok && ((unsigned)ix < 64u)) ? xb[(ci * HW_ + iy) * HW_ + ix] : 0.f;
                float q = rintf(v * inv_p);
                xs[ci * 9 + ky * 3 + kx] = fminf(32767.f, fmaxf(-32767.f, q));
            }
        }

    float acc[32];
    const float* wr = ws + CWINT_F + ch * (32 * 27);  // uniform -> s_load
    #pragma unroll
    for (int c = 0; c < 32; c++) {
        float a = 0.f;
        #pragma unroll
        for (int k = 0; k < 27; k++) a = fmaf(xs[k], wr[c * 27 + k], a);
        acc[c] = a;
    }

    float mx = 0.f;
    const size_t base = (size_t)b * FIN + (size_t)ch * 32 * 1024 + oy * 32 + ox;
    #pragma unroll
    for (int c = 0; c < 32; c++) {
        const int co = ch * 32 + c;
        float h = (acc[c] + ws[CBINT_F + co]) * ws[CBSF_F + co];
        h = fmaxf(h, 0.f);
        mx = fmaxf(mx, h);
        h16[base + (size_t)c * 1024] = __half_as_ushort(__float2half(h));
    }
    float bm = blockMax(mx);
    if (t == 0) atomicMax(maxh, __float_as_uint(bm));
}

// ---- kernel 5: split-K f16 MFMA GEMM, on-the-fly requant of A and B ----
// grid: x = output tile (2x2 of 128x128), y = K slice (256 slices of 256)
// 1024 blocks -> 4 blocks/CU (LDS 37.4KB, VGPR<=128) -> 16 waves/CU for
// latency hiding; was 256 blocks = 1 block/CU = the 9.7% occupancy stall.
__global__ __launch_bounds__(256, 4) void k_gemm(const u16* __restrict__ h16,
                                                 const float* __restrict__ dw,
                                                 const float* __restrict__ ws,
                                                 float* __restrict__ accb) {
    __shared__ __align__(16) _Float16 As[128][72];
    __shared__ __align__(16) _Float16 Bs[128][72];
    __shared__ float invB[128];

    const int tid = threadIdx.x;
    const int tm  = (blockIdx.x >> 1) * 128;
    const int tn  = (blockIdx.x & 1) * 128;
    const int k0  = blockIdx.y * 256;

    const float max_h  = __uint_as_float(((const unsigned*)ws)[SC_F + 1]);
    const float p2     = fmaxf(max_h, 1e-8f) / 1023.0f;
    const float inv_p2 = 1.0f / p2;

    if (tid < 128) {
        float am = fmaxf(__uint_as_float(((const unsigned*)ws)[WSF2_F + tn + tid]), 1e-8f);
        invB[tid] = 127.0f / am;
    }

    floatx4 acc[4][4];
    const floatx4 zz = {0.f, 0.f, 0.f, 0.f};
    #pragma unroll
    for (int i = 0; i < 4; i++)
        #pragma unroll
        for (int j = 0; j < 4; j++) acc[i][j] = zz;

    const int wv = tid >> 6, lane = tid & 63;
    const int wm = (wv >> 1) * 64, wn = (wv & 1) * 64;
    const int lm = lane & 15, quad = lane >> 4;

    for (int kk = 0; kk < 4; kk++) {
        __syncthreads();
        // stage A: 128 rows x 64 halves, requant h -> int-valued f16
        #pragma unroll
        for (int r = 0; r < 4; r++) {
            const int i = tid + r * 256;
            const int row = i >> 3, c = i & 7;
            const u16* p = h16 + (size_t)(tm + row) * FIN + k0 + kk * 64 + c * 8;
            half8 hv = *(const half8*)p;
            half8 qv;
            #pragma unroll
            for (int j = 0; j < 8; j++) {
                float f = (float)hv[j];
                qv[j] = (_Float16)fminf(1023.f, rintf(f * inv_p2));
            }
            *(half8*)&As[row][c * 8] = qv;
        }
        // stage B: 128 rows x 64 floats, quantize w -> int-valued f16
        #pragma unroll
        for (int r = 0; r < 8; r++) {
            const int i = tid + r * 256;
            const int row = i >> 4, c = i & 15;
            const float* p = dw + (size_t)(tn + row) * FIN + k0 + kk * 64 + c * 4;
            float4 v = *(const float4*)p;
            const float is = invB[row];
            half4v qv;
            qv[0] = (_Float16)fminf(127.f, fmaxf(-127.f, rintf(v.x * is)));
            qv[1] = (_Float16)fminf(127.f, fmaxf(-127.f, rintf(v.y * is)));
            qv[2] = (_Float16)fminf(127.f, fmaxf(-127.f, rintf(v.z * is)));
            qv[3] = (_Float16)fminf(127.f, fmaxf(-127.f, rintf(v.w * is)));
            *(half4v*)&Bs[row][c * 4] = qv;
        }
        __syncthreads();
        #pragma unroll
        for (int ks = 0; ks < 2; ks++) {
            half8 af[4], bf[4];
            #pragma unroll
            for (int mi = 0; mi < 4; mi++)
                af[mi] = *(const half8*)&As[wm + mi * 16 + lm][ks * 32 + quad * 8];
            #pragma unroll
            for (int ni = 0; ni < 4; ni++)
                bf[ni] = *(const half8*)&Bs[wn + ni * 16 + lm][ks * 32 + quad * 8];
            #pragma unroll
            for (int mi = 0; mi < 4; mi++)
                #pragma unroll
                for (int ni = 0; ni < 4; ni++)
                    acc[mi][ni] = __builtin_amdgcn_mfma_f32_16x16x32_f16(af[mi], bf[ni], acc[mi][ni], 0, 0, 0);
        }
    }

    #pragma unroll
    for (int mi = 0; mi < 4; mi++)
        #pragma unroll
        for (int ni = 0; ni < 4; ni++)
            #pragma unroll
            for (int r = 0; r < 4; r++) {
                const int row = tm + wm + mi * 16 + quad * 4 + r;
                const int col = tn + wn + ni * 16 + lm;
                atomicAdd(accb + row * FOUT + col, acc[mi][ni][r]);
            }
}

// ---- kernel 6: epilogue: +b_int, *bias_sf, relu ----
__global__ void k_epi(const float* __restrict__ accb, const float* __restrict__ db,
                      const float* __restrict__ ws, float* __restrict__ out) {
    const int idx = blockIdx.x * 256 + threadIdx.x;
    const int n = idx & 255;
    const float max_h = __uint_as_float(((const unsigned*)ws)[SC_F + 1]);
    const float p2 = fmaxf(max_h, 1e-8f) / 1023.0f;
    const float am = fmaxf(__uint_as_float(((const unsigned*)ws)[WSF2_F + n]), 1e-8f);
    const float wsf = am / 127.0f;
    const float bsf = p2 * wsf;
    const float bint = rintf(db[n] / bsf);
    out[idx] = fmaxf(0.f, (accb[idx] + bint) * bsf);
}

extern "C" void kernel_launch(void* const* d_in, const int* in_sizes, int n_in,
                              void* d_out, int out_size, void* d_ws, size_t ws_size,
                              hipStream_t stream) {
    (void)in_sizes; (void)n_in; (void)out_size; (void)ws_size;
    const float* x  = (const float*)d_in[0];
    const float* cw = (const float*)d_in[1];
    const float* cb = (const float*)d_in[2];
    const float* dw = (const float*)d_in[3];
    const float* db = (const float*)d_in[4];
    float* out = (float*)d_out;
    float* ws  = (float*)d_ws;
    u16* h16   = (u16*)((char*)d_ws + H16_BYTE);
    float* accb = ws + ACC_F;
    unsigned* scal = (unsigned*)(ws + SC_F);
    unsigned* wabs = (unsigned*)(ws + WSF2_F);

    // zero GEMM accumulator + atomic-max slots + per-row absmax slots
    hipMemsetAsync(d_ws, 0, (size_t)(65536 + 16 + 256) * sizeof(float), stream);

    k_amax_x<<<512, 256, 0, stream>>>(x, scal + 0, (B_ * CIN * HW_ * HW_) / 4);
    k_wamax<<<1024, 256, 0, stream>>>(dw, wabs);
    k_qconvw<<<1, 64, 0, stream>>>(cw, cb, ws);
    k_conv<<<2048, 256, 0, stream>>>(x, ws, h16, scal + 1);
    k_gemm<<<dim3(4, 256), 256, 0, stream>>>(h16, dw, ws, accb);
    k_epi<<<256, 256, 0, stream>>>(accb, db, ws, out);
}

// Round 2
// 231.481 us; speedup vs baseline: 1.0837x; 1.0837x over previous
//
#include <hip/hip_runtime.h>
#include <hip/hip_fp16.h>
#include <cstdint>

// Problem shape
#define B_   256
#define CIN  3
#define HW_  64
#define COUT 64
#define FIN  65536   // 64*32*32
#define FOUT 256

// Workspace layout (float indices)
#define ACC_F    0        // 65536: split-K GEMM accumulator (zeroed by k_conv)
#define SC_F     65536    // 16: [1] = max_h bits (atomicMax; zeroed by k_stats)
#define XPART_F  65552    // 512: per-block partial absmax of x (plain writes)
#define WPART_F  66064    // 1024: per-(row,quarter) partial absmax of dense_w
#define CSF_F    67088    // 64: conv per-channel weight scale
#define CWINT_F  67152    // 1728: conv w_int (float-valued, s_load path in k_conv)
#define H16_BYTE (512*1024)  // f16 h buffer, 33.5 MB

typedef _Float16 half8  __attribute__((ext_vector_type(8)));
typedef _Float16 half4v __attribute__((ext_vector_type(4)));
typedef float    floatx4 __attribute__((ext_vector_type(4)));
typedef unsigned short u16;

__device__ inline float blockMax(float v) {
    #pragma unroll
    for (int off = 32; off; off >>= 1) v = fmaxf(v, __shfl_down(v, off));
    __shared__ float sm[8];
    const int lane = threadIdx.x & 63, w = threadIdx.x >> 6;
    if (lane == 0) sm[w] = v;
    __syncthreads();
    float m = sm[0];
    const int nw = blockDim.x >> 6;
    for (int i = 1; i < nw; i++) m = fmaxf(m, sm[i]);
    return m;
}

// ---- kernel 1: all input statistics + conv weight quant, ONE launch ----
// blocks [0,512): partial absmax of x -> XPART (plain writes, no pre-zero)
// blocks [512,1536): partial per-row absmax of dense_w -> WPART
// block 1536: quantize conv weights (needs no p_sf), zero the max_h slot
__global__ __launch_bounds__(256) void k_stats(const float* __restrict__ x,
                                               const float* __restrict__ dw,
                                               const float* __restrict__ cw,
                                               float* __restrict__ ws) {
    const int b = blockIdx.x;
    const int t = threadIdx.x;
    if (b < 512) {
        const float4* x4 = (const float4*)x;
        float m = 0.f;
        for (int i = b * 256 + t; i < (B_ * CIN * HW_ * HW_) / 4; i += 512 * 256) {
            float4 v = x4[i];
            m = fmaxf(m, fmaxf(fmaxf(fabsf(v.x), fabsf(v.y)), fmaxf(fabsf(v.z), fabsf(v.w))));
        }
        float bm = blockMax(m);
        if (t == 0) ws[XPART_F + b] = bm;
    } else if (b < 1536) {
        const int b2 = b - 512;
        const int row = b2 >> 2, q = b2 & 3;
        const float4* r = (const float4*)(dw + (size_t)row * FIN) + q * 4096;
        float m = 0.f;
        for (int i = t; i < 4096; i += 256) {
            float4 v = r[i];
            m = fmaxf(m, fmaxf(fmaxf(fabsf(v.x), fabsf(v.y)), fmaxf(fabsf(v.z), fabsf(v.w))));
        }
        float bm = blockMax(m);
        if (t == 0) ws[WPART_F + b2] = bm;
    } else {
        if (t == 64) ((unsigned*)ws)[SC_F + 1] = 0u;   // zero max_h slot for k_conv's atomicMax
        if (t < 64) {
            const int o = t;
            float wv[27];
            float m = 0.f;
            #pragma unroll
            for (int i = 0; i < 27; i++) { wv[i] = cw[o * 27 + i]; m = fmaxf(m, fabsf(wv[i])); }
            const float sf = fmaxf(m, 1e-8f) / 127.0f;
            #pragma unroll
            for (int i = 0; i < 27; i++)
                ws[CWINT_F + o * 27 + i] = fminf(127.f, fmaxf(-127.f, rintf(wv[i] / sf)));
            ws[CSF_F + o] = sf;
        }
    }
}

// ---- kernel 2: conv 3x3 s2 p1, relu, f16 store, global max(h) ----
// Also: reduces x-partials -> p_sf, computes bias scales, zeroes accb.
__global__ __launch_bounds__(256) void k_conv(const float* __restrict__ x,
                                              const float* __restrict__ cb,
                                              float* __restrict__ ws,
                                              u16* __restrict__ h16) {
    __shared__ float s_bsf[64], s_bint[64];
    const int t = threadIdx.x;
    // zero the GEMM accumulator (visible to k_gemm at kernel boundary)
    if (blockIdx.x < 256) ws[ACC_F + blockIdx.x * 256 + t] = 0.f;
    // p_sf from the 512 x-partials
    float pm = fmaxf(ws[XPART_F + t], ws[XPART_F + 256 + t]);
    pm = blockMax(pm);
    const float p_sf = fmaxf(pm, 1e-8f) / 32767.0f;
    const float inv_p = 1.0f / p_sf;
    if (t < 64) {
        const float bsf = p_sf * ws[CSF_F + t];
        s_bsf[t]  = bsf;
        s_bint[t] = rintf(cb[t] / bsf);
    }
    __syncthreads();

    const int b   = blockIdx.x >> 3;
    const int oyt = (blockIdx.x & 7) * 4;
    const int ox  = t & 31;
    const int ch  = __builtin_amdgcn_readfirstlane((t >> 6) & 1);  // wave-uniform
    const int oy  = oyt + ((t >> 7) << 1) + ((t >> 5) & 1);
    const float* xb = x + (size_t)b * (CIN * HW_ * HW_);

    float xs[27];
    #pragma unroll
    for (int ci = 0; ci < 3; ci++)
        #pragma unroll
        for (int ky = 0; ky < 3; ky++) {
            const int iy = 2 * oy - 1 + ky;
            const bool yok = ((unsigned)iy < 64u);
            #pragma unroll
            for (int kx = 0; kx < 3; kx++) {
                const int ix = 2 * ox - 1 + kx;
                float v = (yok && ((unsigned)ix < 64u)) ? xb[(ci * HW_ + iy) * HW_ + ix] : 0.f;
                float q = rintf(v * inv_p);
                xs[ci * 9 + ky * 3 + kx] = fminf(32767.f, fmaxf(-32767.f, q));
            }
        }

    float acc[32];
    const float* wr = ws + CWINT_F + ch * (32 * 27);  // uniform -> s_load
    #pragma unroll
    for (int c = 0; c < 32; c++) {
        float a = 0.f;
        #pragma unroll
        for (int k = 0; k < 27; k++) a = fmaf(xs[k], wr[c * 27 + k], a);
        acc[c] = a;
    }

    float mx = 0.f;
    const size_t base = (size_t)b * FIN + (size_t)ch * 32 * 1024 + oy * 32 + ox;
    #pragma unroll
    for (int c = 0; c < 32; c++) {
        const int co = ch * 32 + c;
        float h = (acc[c] + s_bint[co]) * s_bsf[co];
        h = fmaxf(h, 0.f);
        mx = fmaxf(mx, h);
        h16[base + (size_t)c * 1024] = __half_as_ushort(__float2half(h));
    }
    float bm = blockMax(mx);
    if (t == 0) atomicMax((unsigned*)ws + SC_F + 1, __float_as_uint(bm));
}

// ---- kernel 3: split-K f16 MFMA GEMM, reg-staged async double buffer ----
// grid: x = output tile (2x2 of 128x128), y = K slice (128 slices of 512)
// 512 blocks -> 2 blocks/CU. T14: issue next tile's global loads before the
// MFMA phase so HBM latency hides under compute + the co-resident block.
__global__ __launch_bounds__(256, 2) void k_gemm(const u16* __restrict__ h16,
                                                 const float* __restrict__ dw,
                                                 const float* __restrict__ ws,
                                                 float* __restrict__ accb) {
    __shared__ __align__(16) _Float16 As[128][72];
    __shared__ __align__(16) _Float16 Bs[128][72];
    __shared__ float invB[128];

    const int tid = threadIdx.x;
    const int tm  = (blockIdx.x >> 1) * 128;
    const int tn  = (blockIdx.x & 1) * 128;
    const int k0  = blockIdx.y * 512;

    const float max_h  = __uint_as_float(((const unsigned*)ws)[SC_F + 1]);
    const float p2     = fmaxf(max_h, 1e-8f) / 1023.0f;
    const float inv_p2 = 1.0f / p2;

    if (tid < 128) {
        const float* wp = ws + WPART_F + (size_t)(tn + tid) * 4;
        const float am = fmaxf(fmaxf(wp[0], wp[1]), fmaxf(wp[2], wp[3]));
        invB[tid] = 127.0f / fmaxf(am, 1e-8f);
    }

    floatx4 acc[4][4];
    const floatx4 zz = {0.f, 0.f, 0.f, 0.f};
    #pragma unroll
    for (int i = 0; i < 4; i++)
        #pragma unroll
        for (int j = 0; j < 4; j++) acc[i][j] = zz;

    const int wv = tid >> 6, lane = tid & 63;
    const int wm = (wv >> 1) * 64, wn = (wv & 1) * 64;
    const int lm = lane & 15, quad = lane >> 4;

    const int arow = tid >> 3, acol = tid & 7;    // A: 4 chunks/thread, rows +32
    const int brow = tid >> 4, bcol = tid & 15;   // B: 8 chunks/thread, rows +16

    half8  areg[4];
    float4 breg[8];

    // issue kk=0 loads immediately (before barrier; no LDS dependence)
    #pragma unroll
    for (int r = 0; r < 4; r++)
        areg[r] = *(const half8*)(h16 + (size_t)(tm + arow + r * 32) * FIN + k0 + acol * 8);
    #pragma unroll
    for (int r = 0; r < 8; r++)
        breg[r] = *(const float4*)(dw + (size_t)(tn + brow + r * 16) * FIN + k0 + bcol * 4);

    __syncthreads();   // invB ready

    for (int kk = 0; kk < 8; kk++) {
        // write-late: requantize staged regs into LDS
        #pragma unroll
        for (int r = 0; r < 4; r++) {
            half8 qv;
            #pragma unroll
            for (int j = 0; j < 8; j++) {
                float f = (float)areg[r][j];
                qv[j] = (_Float16)fminf(1023.f, rintf(f * inv_p2));
            }
            *(half8*)&As[arow + r * 32][acol * 8] = qv;
        }
        #pragma unroll
        for (int r = 0; r < 8; r++) {
            const float is = invB[brow + r * 16];
            float4 v = breg[r];
            half4v qv;
            qv[0] = (_Float16)fminf(127.f, fmaxf(-127.f, rintf(v.x * is)));
            qv[1] = (_Float16)fminf(127.f, fmaxf(-127.f, rintf(v.y * is)));
            qv[2] = (_Float16)fminf(127.f, fmaxf(-127.f, rintf(v.z * is)));
            qv[3] = (_Float16)fminf(127.f, fmaxf(-127.f, rintf(v.w * is)));
            *(half4v*)&Bs[brow + r * 16][bcol * 4] = qv;
        }
        __syncthreads();

        // issue-early: next tile's global loads fly during the MFMA phase
        if (kk < 7) {
            const int kn = k0 + (kk + 1) * 64;
            #pragma unroll
            for (int r = 0; r < 4; r++)
                areg[r] = *(const half8*)(h16 + (size_t)(tm + arow + r * 32) * FIN + kn + acol * 8);
            #pragma unroll
            for (int r = 0; r < 8; r++)
                breg[r] = *(const float4*)(dw + (size_t)(tn + brow + r * 16) * FIN + kn + bcol * 4);
        }

        #pragma unroll
        for (int ks = 0; ks < 2; ks++) {
            half8 af[4], bf[4];
            #pragma unroll
            for (int mi = 0; mi < 4; mi++)
                af[mi] = *(const half8*)&As[wm + mi * 16 + lm][ks * 32 + quad * 8];
            #pragma unroll
            for (int ni = 0; ni < 4; ni++)
                bf[ni] = *(const half8*)&Bs[wn + ni * 16 + lm][ks * 32 + quad * 8];
            #pragma unroll
            for (int mi = 0; mi < 4; mi++)
                #pragma unroll
                for (int ni = 0; ni < 4; ni++)
                    acc[mi][ni] = __builtin_amdgcn_mfma_f32_16x16x32_f16(af[mi], bf[ni], acc[mi][ni], 0, 0, 0);
        }
        __syncthreads();   // LDS consumed; safe to overwrite next iteration
    }

    #pragma unroll
    for (int mi = 0; mi < 4; mi++)
        #pragma unroll
        for (int ni = 0; ni < 4; ni++)
            #pragma unroll
            for (int r = 0; r < 4; r++) {
                const int row = tm + wm + mi * 16 + quad * 4 + r;
                const int col = tn + wn + ni * 16 + lm;
                atomicAdd(accb + row * FOUT + col, acc[mi][ni][r]);
            }
}

// ---- kernel 4: epilogue: +b_int, *bias_sf, relu ----
__global__ void k_epi(const float* __restrict__ accb, const float* __restrict__ db,
                      const float* __restrict__ ws, float* __restrict__ out) {
    const int idx = blockIdx.x * 256 + threadIdx.x;
    const int n = idx & 255;
    const float max_h = __uint_as_float(((const unsigned*)ws)[SC_F + 1]);
    const float p2 = fmaxf(max_h, 1e-8f) / 1023.0f;
    const float* wp = ws + WPART_F + (size_t)n * 4;
    const float am = fmaxf(fmaxf(fmaxf(wp[0], wp[1]), fmaxf(wp[2], wp[3])), 1e-8f);
    const float wsf = am / 127.0f;
    const float bsf = p2 * wsf;
    const float bint = rintf(db[n] / bsf);
    out[idx] = fmaxf(0.f, (accb[idx] + bint) * bsf);
}

extern "C" void kernel_launch(void* const* d_in, const int* in_sizes, int n_in,
                              void* d_out, int out_size, void* d_ws, size_t ws_size,
                              hipStream_t stream) {
    (void)in_sizes; (void)n_in; (void)out_size; (void)ws_size;
    const float* x  = (const float*)d_in[0];
    const float* cw = (const float*)d_in[1];
    const float* cb = (const float*)d_in[2];
    const float* dw = (const float*)d_in[3];
    const float* db = (const float*)d_in[4];
    float* out = (float*)d_out;
    float* ws  = (float*)d_ws;
    u16* h16   = (u16*)((char*)d_ws + H16_BYTE);
    float* accb = ws + ACC_F;

    // 4 enqueues, no memset: stats -> conv -> gemm -> epilogue
    k_stats<<<1537, 256, 0, stream>>>(x, dw, cw, ws);
    k_conv<<<2048, 256, 0, stream>>>(x, cb, ws, h16);
    k_gemm<<<dim3(4, 128), 256, 0, stream>>>(h16, dw, ws, accb);
    k_epi<<<256, 256, 0, stream>>>(accb, db, ws, out);
}

// Round 3
// 225.372 us; speedup vs baseline: 1.1131x; 1.0271x over previous
//
#include <hip/hip_runtime.h>
#include <hip/hip_fp16.h>
#include <cstdint>

// Problem shape
#define B_   256
#define CIN  3
#define HW_  64
#define COUT 64
#define FIN  65536   // 64*32*32
#define FOUT 256

// Workspace layout (float indices)
#define ACC_F    0        // 65536: split-K GEMM accumulator (zeroed by k_stats)
#define SC_F     65536    // 16: [1] = max_h bits (atomicMax; zeroed by k_stats)
#define XPART_F  65552    // 512: per-block partial absmax of x (plain writes)
#define WPART_F  66064    // 1024: per-(row,quarter) partial absmax of dense_w
#define CSF_F    67088    // 64: conv per-channel weight scale
#define CWINT_F  67152    // 1728: conv w_int (float-valued, s_load path in k_conv)
#define H16_BYTE (512*1024)  // f16 h buffer, 33.5 MB

typedef _Float16 half8  __attribute__((ext_vector_type(8)));
typedef _Float16 half4v __attribute__((ext_vector_type(4)));
typedef float    floatx4 __attribute__((ext_vector_type(4)));
typedef unsigned short u16;

__device__ inline float blockMax(float v) {
    #pragma unroll
    for (int off = 32; off; off >>= 1) v = fmaxf(v, __shfl_down(v, off));
    __shared__ float sm[8];
    const int lane = threadIdx.x & 63, w = threadIdx.x >> 6;
    if (lane == 0) sm[w] = v;
    __syncthreads();
    float m = sm[0];
    const int nw = blockDim.x >> 6;
    for (int i = 1; i < nw; i++) m = fmaxf(m, sm[i]);
    return m;
}

// ---- kernel 1: all input statistics + conv weight quant + accb zero ----
// blocks [0,512): partial absmax of x -> XPART (plain writes, no pre-zero)
// blocks [512,1536): partial per-row absmax of dense_w -> WPART
// block 1536: quantize conv weights (needs no p_sf), zero the max_h slot
// blocks [1537,1793): zero the 256KB GEMM accumulator
__global__ __launch_bounds__(256) void k_stats(const float* __restrict__ x,
                                               const float* __restrict__ dw,
                                               const float* __restrict__ cw,
                                               float* __restrict__ ws) {
    const int b = blockIdx.x;
    const int t = threadIdx.x;
    if (b < 512) {
        const float4* x4 = (const float4*)x;
        float m = 0.f;
        for (int i = b * 256 + t; i < (B_ * CIN * HW_ * HW_) / 4; i += 512 * 256) {
            float4 v = x4[i];
            m = fmaxf(m, fmaxf(fmaxf(fabsf(v.x), fabsf(v.y)), fmaxf(fabsf(v.z), fabsf(v.w))));
        }
        float bm = blockMax(m);
        if (t == 0) ws[XPART_F + b] = bm;
    } else if (b < 1536) {
        const int b2 = b - 512;
        const int row = b2 >> 2, q = b2 & 3;
        const float4* r = (const float4*)(dw + (size_t)row * FIN) + q * 4096;
        float m = 0.f;
        for (int i = t; i < 4096; i += 256) {
            float4 v = r[i];
            m = fmaxf(m, fmaxf(fmaxf(fabsf(v.x), fabsf(v.y)), fmaxf(fabsf(v.z), fabsf(v.w))));
        }
        float bm = blockMax(m);
        if (t == 0) ws[WPART_F + b2] = bm;
    } else if (b == 1536) {
        if (t == 64) ((unsigned*)ws)[SC_F + 1] = 0u;   // zero max_h slot for k_conv's atomicMax
        if (t < 64) {
            const int o = t;
            float wv[27];
            float m = 0.f;
            #pragma unroll
            for (int i = 0; i < 27; i++) { wv[i] = cw[o * 27 + i]; m = fmaxf(m, fabsf(wv[i])); }
            const float sf = fmaxf(m, 1e-8f) / 127.0f;
            #pragma unroll
            for (int i = 0; i < 27; i++)
                ws[CWINT_F + o * 27 + i] = fminf(127.f, fmaxf(-127.f, rintf(wv[i] / sf)));
            ws[CSF_F + o] = sf;
        }
    } else {
        // zero GEMM accumulator (visible to k_gemm at kernel boundary)
        ws[ACC_F + (b - 1537) * 256 + t] = 0.f;
    }
}

// ---- kernel 2: conv 3x3 s2 p1, relu, f16 store, global max(h) ----
// ws is CONST + RESTRICT so the wave-uniform weight reads compile to s_load
// (r2 made ws writable -> weights fell off the scalar path -> 86us. Never
// write through the pointer the weight s_loads come from.)
// x is staged in LDS: coalesced float4 loads, requant once per input pixel,
// halo column so inner reads are unconditional (lane-stride-2 = free 2-way).
__global__ __launch_bounds__(256) void k_conv(const float* __restrict__ x,
                                              const float* __restrict__ cb,
                                              const float* __restrict__ ws,
                                              u16* __restrict__ h16,
                                              unsigned* __restrict__ maxh) {
    __shared__ float s_bsf[64], s_bint[64];
    __shared__ float xt[27 * 68];   // [ci*9+lr][68]: col 0 = ix=-1 halo, col 65 = ix=64 halo
    const int t = threadIdx.x;

    // p_sf from the 512 x-partials (blockMax contains the needed syncthreads)
    float pm = fmaxf(ws[XPART_F + t], ws[XPART_F + 256 + t]);
    pm = blockMax(pm);
    const float p_sf = fmaxf(pm, 1e-8f) / 32767.0f;
    const float inv_p = 1.0f / p_sf;
    if (t < 64) {
        const float bsf = p_sf * ws[CSF_F + t];
        s_bsf[t]  = bsf;
        s_bint[t] = rintf(cb[t] / bsf);
    }

    const int b   = blockIdx.x >> 3;
    const int oyt = (blockIdx.x & 7) * 4;
    const float* xb = x + (size_t)b * (CIN * HW_ * HW_);

    // stage 27 rows x 64 cols, requantized; 432 float4 chunks over 256 threads
    for (int i = t; i < 432; i += 256) {
        const int lrow = i >> 4, c4 = i & 15;
        const int ci = lrow / 9, lr = lrow - ci * 9;
        const int iy = 2 * oyt - 1 + lr;
        float4 v = make_float4(0.f, 0.f, 0.f, 0.f);
        if ((unsigned)iy < 64u) v = *(const float4*)(xb + (ci * HW_ + iy) * HW_ + c4 * 4);
        float* d = &xt[lrow * 68 + 1 + c4 * 4];
        d[0] = fminf(32767.f, fmaxf(-32767.f, rintf(v.x * inv_p)));
        d[1] = fminf(32767.f, fmaxf(-32767.f, rintf(v.y * inv_p)));
        d[2] = fminf(32767.f, fmaxf(-32767.f, rintf(v.z * inv_p)));
        d[3] = fminf(32767.f, fmaxf(-32767.f, rintf(v.w * inv_p)));
    }
    if (t < 27) xt[t * 68] = 0.f;                      // ix = -1 halo
    else if (t < 54) xt[(t - 27) * 68 + 65] = 0.f;     // ix = 64 halo
    __syncthreads();

    const int ox = t & 31;
    const int ch = __builtin_amdgcn_readfirstlane((t >> 6) & 1);  // wave-uniform
    const int dy = ((t >> 7) << 1) + ((t >> 5) & 1);              // 0..3
    const int oy = oyt + dy;

    float xs[27];
    #pragma unroll
    for (int ci = 0; ci < 3; ci++)
        #pragma unroll
        for (int ky = 0; ky < 3; ky++) {
            const int lr = 2 * dy + ky;
            const float* rowp = &xt[(ci * 9 + lr) * 68 + 2 * ox];  // col = 2ox+kx <-> ix = 2ox-1+kx
            #pragma unroll
            for (int kx = 0; kx < 3; kx++)
                xs[ci * 9 + ky * 3 + kx] = rowp[kx];
        }

    float acc[32];
    const float* wr = ws + CWINT_F + ch * (32 * 27);  // uniform + const -> s_load
    #pragma unroll
    for (int c = 0; c < 32; c++) {
        float a = 0.f;
        #pragma unroll
        for (int k = 0; k < 27; k++) a = fmaf(xs[k], wr[c * 27 + k], a);
        acc[c] = a;
    }

    float mx = 0.f;
    const size_t base = (size_t)b * FIN + (size_t)ch * 32 * 1024 + oy * 32 + ox;
    #pragma unroll
    for (int c = 0; c < 32; c++) {
        const int co = ch * 32 + c;
        float h = (acc[c] + s_bint[co]) * s_bsf[co];
        h = fmaxf(h, 0.f);
        mx = fmaxf(mx, h);
        h16[base + (size_t)c * 1024] = __half_as_ushort(__float2half(h));
    }
    float bm = blockMax(mx);
    if (t == 0) atomicMax(maxh, __float_as_uint(bm));
}

// ---- kernel 3: split-K f16 MFMA GEMM, reg-staged async double buffer ----
// grid: x = output tile (2x2 of 128x128), y = K slice (128 slices of 512)
// 512 blocks -> 2 blocks/CU. T14: issue next tile's global loads before the
// MFMA phase so HBM latency hides under compute + the co-resident block.
__global__ __launch_bounds__(256, 2) void k_gemm(const u16* __restrict__ h16,
                                                 const float* __restrict__ dw,
                                                 const float* __restrict__ ws,
                                                 float* __restrict__ accb) {
    __shared__ __align__(16) _Float16 As[128][72];
    __shared__ __align__(16) _Float16 Bs[128][72];
    __shared__ float invB[128];

    const int tid = threadIdx.x;
    const int tm  = (blockIdx.x >> 1) * 128;
    const int tn  = (blockIdx.x & 1) * 128;
    const int k0  = blockIdx.y * 512;

    const float max_h  = __uint_as_float(((const unsigned*)ws)[SC_F + 1]);
    const float p2     = fmaxf(max_h, 1e-8f) / 1023.0f;
    const float inv_p2 = 1.0f / p2;

    if (tid < 128) {
        const float* wp = ws + WPART_F + (size_t)(tn + tid) * 4;
        const float am = fmaxf(fmaxf(wp[0], wp[1]), fmaxf(wp[2], wp[3]));
        invB[tid] = 127.0f / fmaxf(am, 1e-8f);
    }

    floatx4 acc[4][4];
    const floatx4 zz = {0.f, 0.f, 0.f, 0.f};
    #pragma unroll
    for (int i = 0; i < 4; i++)
        #pragma unroll
        for (int j = 0; j < 4; j++) acc[i][j] = zz;

    const int wv = tid >> 6, lane = tid & 63;
    const int wm = (wv >> 1) * 64, wn = (wv & 1) * 64;
    const int lm = lane & 15, quad = lane >> 4;

    const int arow = tid >> 3, acol = tid & 7;    // A: 4 chunks/thread, rows +32
    const int brow = tid >> 4, bcol = tid & 15;   // B: 8 chunks/thread, rows +16

    half8  areg[4];
    float4 breg[8];

    // issue kk=0 loads immediately (before barrier; no LDS dependence)
    #pragma unroll
    for (int r = 0; r < 4; r++)
        areg[r] = *(const half8*)(h16 + (size_t)(tm + arow + r * 32) * FIN + k0 + acol * 8);
    #pragma unroll
    for (int r = 0; r < 8; r++)
        breg[r] = *(const float4*)(dw + (size_t)(tn + brow + r * 16) * FIN + k0 + bcol * 4);

    __syncthreads();   // invB ready

    for (int kk = 0; kk < 8; kk++) {
        // write-late: requantize staged regs into LDS
        #pragma unroll
        for (int r = 0; r < 4; r++) {
            half8 qv;
            #pragma unroll
            for (int j = 0; j < 8; j++) {
                float f = (float)areg[r][j];
                qv[j] = (_Float16)fminf(1023.f, rintf(f * inv_p2));
            }
            *(half8*)&As[arow + r * 32][acol * 8] = qv;
        }
        #pragma unroll
        for (int r = 0; r < 8; r++) {
            const float is = invB[brow + r * 16];
            float4 v = breg[r];
            half4v qv;
            qv[0] = (_Float16)fminf(127.f, fmaxf(-127.f, rintf(v.x * is)));
            qv[1] = (_Float16)fminf(127.f, fmaxf(-127.f, rintf(v.y * is)));
            qv[2] = (_Float16)fminf(127.f, fmaxf(-127.f, rintf(v.z * is)));
            qv[3] = (_Float16)fminf(127.f, fmaxf(-127.f, rintf(v.w * is)));
            *(half4v*)&Bs[brow + r * 16][bcol * 4] = qv;
        }
        __syncthreads();

        // issue-early: next tile's global loads fly during the MFMA phase
        if (kk < 7) {
            const int kn = k0 + (kk + 1) * 64;
            #pragma unroll
            for (int r = 0; r < 4; r++)
                areg[r] = *(const half8*)(h16 + (size_t)(tm + arow + r * 32) * FIN + kn + acol * 8);
            #pragma unroll
            for (int r = 0; r < 8; r++)
                breg[r] = *(const float4*)(dw + (size_t)(tn + brow + r * 16) * FIN + kn + bcol * 4);
        }

        #pragma unroll
        for (int ks = 0; ks < 2; ks++) {
            half8 af[4], bf[4];
            #pragma unroll
            for (int mi = 0; mi < 4; mi++)
                af[mi] = *(const half8*)&As[wm + mi * 16 + lm][ks * 32 + quad * 8];
            #pragma unroll
            for (int ni = 0; ni < 4; ni++)
                bf[ni] = *(const half8*)&Bs[wn + ni * 16 + lm][ks * 32 + quad * 8];
            #pragma unroll
            for (int mi = 0; mi < 4; mi++)
                #pragma unroll
                for (int ni = 0; ni < 4; ni++)
                    acc[mi][ni] = __builtin_amdgcn_mfma_f32_16x16x32_f16(af[mi], bf[ni], acc[mi][ni], 0, 0, 0);
        }
        __syncthreads();   // LDS consumed; safe to overwrite next iteration
    }

    #pragma unroll
    for (int mi = 0; mi < 4; mi++)
        #pragma unroll
        for (int ni = 0; ni < 4; ni++)
            #pragma unroll
            for (int r = 0; r < 4; r++) {
                const int row = tm + wm + mi * 16 + quad * 4 + r;
                const int col = tn + wn + ni * 16 + lm;
                atomicAdd(accb + row * FOUT + col, acc[mi][ni][r]);
            }
}

// ---- kernel 4: epilogue: +b_int, *bias_sf, relu ----
__global__ void k_epi(const float* __restrict__ accb, const float* __restrict__ db,
                      const float* __restrict__ ws, float* __restrict__ out) {
    const int idx = blockIdx.x * 256 + threadIdx.x;
    const int n = idx & 255;
    const float max_h = __uint_as_float(((const unsigned*)ws)[SC_F + 1]);
    const float p2 = fmaxf(max_h, 1e-8f) / 1023.0f;
    const float* wp = ws + WPART_F + (size_t)n * 4;
    const float am = fmaxf(fmaxf(fmaxf(wp[0], wp[1]), fmaxf(wp[2], wp[3])), 1e-8f);
    const float wsf = am / 127.0f;
    const float bsf = p2 * wsf;
    const float bint = rintf(db[n] / bsf);
    out[idx] = fmaxf(0.f, (accb[idx] + bint) * bsf);
}

extern "C" void kernel_launch(void* const* d_in, const int* in_sizes, int n_in,
                              void* d_out, int out_size, void* d_ws, size_t ws_size,
                              hipStream_t stream) {
    (void)in_sizes; (void)n_in; (void)out_size; (void)ws_size;
    const float* x  = (const float*)d_in[0];
    const float* cw = (const float*)d_in[1];
    const float* cb = (const float*)d_in[2];
    const float* dw = (const float*)d_in[3];
    const float* db = (const float*)d_in[4];
    float* out = (float*)d_out;
    float* ws  = (float*)d_ws;
    u16* h16   = (u16*)((char*)d_ws + H16_BYTE);
    float* accb = ws + ACC_F;
    unsigned* maxh = (unsigned*)ws + SC_F + 1;

    // 4 enqueues, no memset: stats -> conv -> gemm -> epilogue
    k_stats<<<1793, 256, 0, stream>>>(x, dw, cw, ws);
    k_conv<<<2048, 256, 0, stream>>>(x, cb, ws, h16, maxh);
    k_gemm<<<dim3(4, 128), 256, 0, stream>>>(h16, dw, ws, accb);
    k_epi<<<256, 256, 0, stream>>>(accb, db, ws, out);
}

// Round 4
// 215.883 us; speedup vs baseline: 1.1620x; 1.0440x over previous
//
#include <hip/hip_runtime.h>
#include <hip/hip_fp16.h>
#include <cstdint>

// Problem shape
#define B_   256
#define CIN  3
#define HW_  64
#define COUT 64
#define FIN  65536   // 64*32*32
#define FOUT 256

// Workspace layout (float indices)
#define ACC_F    0        // 65536: split-K GEMM accumulator (zeroed by k_stats)
#define SC_F     65536    // 16: [1] = max_h bits (atomicMax; zeroed by k_stats)
#define XPART_F  65552    // 512: per-block partial absmax of x (plain writes)
#define WPART_F  66064    // 1024: per-(row,quarter) partial absmax of dense_w
#define CSF_F    67088    // 64: conv per-channel weight scale
#define CWINT_F  67152    // 1728: conv w_int (float-valued, s_load path in k_conv)
#define H16_BYTE (512*1024)  // f16 h buffer, 33.5 MB

typedef _Float16 half8  __attribute__((ext_vector_type(8)));
typedef _Float16 half4v __attribute__((ext_vector_type(4)));
typedef float    floatx4 __attribute__((ext_vector_type(4)));
typedef unsigned short u16;

__device__ inline float blockMax(float v) {
    #pragma unroll
    for (int off = 32; off; off >>= 1) v = fmaxf(v, __shfl_down(v, off));
    __shared__ float sm[8];
    const int lane = threadIdx.x & 63, w = threadIdx.x >> 6;
    if (lane == 0) sm[w] = v;
    __syncthreads();
    float m = sm[0];
    const int nw = blockDim.x >> 6;
    for (int i = 1; i < nw; i++) m = fmaxf(m, sm[i]);
    return m;
}

// ---- kernel 1: all input statistics + conv weight quant + accb zero ----
// blocks [0,512): partial absmax of x -> XPART (plain writes, no pre-zero)
// blocks [512,1536): partial per-row absmax of dense_w -> WPART
// block 1536: quantize conv weights (needs no p_sf), zero the max_h slot
// blocks [1537,1793): zero the 256KB GEMM accumulator
__global__ __launch_bounds__(256) void k_stats(const float* __restrict__ x,
                                               const float* __restrict__ dw,
                                               const float* __restrict__ cw,
                                               float* __restrict__ ws) {
    const int b = blockIdx.x;
    const int t = threadIdx.x;
    if (b < 512) {
        const float4* x4 = (const float4*)x;
        float m = 0.f;
        for (int i = b * 256 + t; i < (B_ * CIN * HW_ * HW_) / 4; i += 512 * 256) {
            float4 v = x4[i];
            m = fmaxf(m, fmaxf(fmaxf(fabsf(v.x), fabsf(v.y)), fmaxf(fabsf(v.z), fabsf(v.w))));
        }
        float bm = blockMax(m);
        if (t == 0) ws[XPART_F + b] = bm;
    } else if (b < 1536) {
        const int b2 = b - 512;
        const int row = b2 >> 2, q = b2 & 3;
        const float4* r = (const float4*)(dw + (size_t)row * FIN) + q * 4096;
        float m = 0.f;
        for (int i = t; i < 4096; i += 256) {
            float4 v = r[i];
            m = fmaxf(m, fmaxf(fmaxf(fabsf(v.x), fabsf(v.y)), fmaxf(fabsf(v.z), fabsf(v.w))));
        }
        float bm = blockMax(m);
        if (t == 0) ws[WPART_F + b2] = bm;
    } else if (b == 1536) {
        if (t == 64) ((unsigned*)ws)[SC_F + 1] = 0u;   // zero max_h slot for k_conv's atomicMax
        if (t < 64) {
            const int o = t;
            float wv[27];
            float m = 0.f;
            #pragma unroll
            for (int i = 0; i < 27; i++) { wv[i] = cw[o * 27 + i]; m = fmaxf(m, fabsf(wv[i])); }
            const float sf = fmaxf(m, 1e-8f) / 127.0f;
            #pragma unroll
            for (int i = 0; i < 27; i++)
                ws[CWINT_F + o * 27 + i] = fminf(127.f, fmaxf(-127.f, rintf(wv[i] / sf)));
            ws[CSF_F + o] = sf;
        }
    } else {
        // zero GEMM accumulator (visible to k_gemm at kernel boundary)
        ws[ACC_F + (b - 1537) * 256 + t] = 0.f;
    }
}

// ---- kernel 2: conv 3x3 s2 p1, relu, f16 store, global max(h) ----
// ws is CONST + RESTRICT so the wave-uniform weight reads compile to s_load.
// x staged in LDS (coalesced, requant once per pixel, halo cols).
// r3 lesson: the compiler REMATERIALIZED xs from LDS (VGPR=36 -> 864
// ds_read/thread -> LDS-issue-bound, 73us). Fix: asm-pin each xs value to a
// VGPR, and use one live accumulator (fused store per channel) instead of
// acc[32] so the allocator has room for all 27 xs.
__global__ __launch_bounds__(256) void k_conv(const float* __restrict__ x,
                                              const float* __restrict__ cb,
                                              const float* __restrict__ ws,
                                              u16* __restrict__ h16,
                                              unsigned* __restrict__ maxh) {
    __shared__ float s_bsf[64], s_bint[64];
    __shared__ float xt[27 * 68];   // [ci*9+lr][68]: col 0 = ix=-1 halo, col 65 = ix=64 halo
    const int t = threadIdx.x;

    // p_sf from the 512 x-partials (blockMax contains the needed syncthreads)
    float pm = fmaxf(ws[XPART_F + t], ws[XPART_F + 256 + t]);
    pm = blockMax(pm);
    const float p_sf = fmaxf(pm, 1e-8f) / 32767.0f;
    const float inv_p = 1.0f / p_sf;
    if (t < 64) {
        const float bsf = p_sf * ws[CSF_F + t];
        s_bsf[t]  = bsf;
        s_bint[t] = rintf(cb[t] / bsf);
    }

    const int b   = blockIdx.x >> 3;
    const int oyt = (blockIdx.x & 7) * 4;
    const float* xb = x + (size_t)b * (CIN * HW_ * HW_);

    // stage 27 rows x 64 cols, requantized; 432 float4 chunks over 256 threads
    for (int i = t; i < 432; i += 256) {
        const int lrow = i >> 4, c4 = i & 15;
        const int ci = lrow / 9, lr = lrow - ci * 9;
        const int iy = 2 * oyt - 1 + lr;
        float4 v = make_float4(0.f, 0.f, 0.f, 0.f);
        if ((unsigned)iy < 64u) v = *(const float4*)(xb + (ci * HW_ + iy) * HW_ + c4 * 4);
        float* d = &xt[lrow * 68 + 1 + c4 * 4];
        d[0] = fminf(32767.f, fmaxf(-32767.f, rintf(v.x * inv_p)));
        d[1] = fminf(32767.f, fmaxf(-32767.f, rintf(v.y * inv_p)));
        d[2] = fminf(32767.f, fmaxf(-32767.f, rintf(v.z * inv_p)));
        d[3] = fminf(32767.f, fmaxf(-32767.f, rintf(v.w * inv_p)));
    }
    if (t < 27) xt[t * 68] = 0.f;                      // ix = -1 halo
    else if (t < 54) xt[(t - 27) * 68 + 65] = 0.f;     // ix = 64 halo
    __syncthreads();

    const int ox = t & 31;
    const int ch = __builtin_amdgcn_readfirstlane((t >> 6) & 1);  // wave-uniform
    const int dy = ((t >> 7) << 1) + ((t >> 5) & 1);              // 0..3
    const int oy = oyt + dy;

    // xs[27] into VGPRs. The empty asm makes each value opaque -> the
    // compiler CANNOT rematerialize the ds_read inside the MAC loop.
    float xs[27];
    #pragma unroll
    for (int ci = 0; ci < 3; ci++)
        #pragma unroll
        for (int ky = 0; ky < 3; ky++) {
            const int lr = 2 * dy + ky;
            const float* rowp = &xt[(ci * 9 + lr) * 68 + 2 * ox];
            #pragma unroll
            for (int kx = 0; kx < 3; kx++) {
                float v = rowp[kx];
                asm volatile("" : "+v"(v));
                xs[ci * 9 + ky * 3 + kx] = v;
            }
        }

    const float* wr = ws + CWINT_F + ch * (32 * 27);  // uniform + const -> s_load
    float mx = 0.f;
    u16* outp = h16 + (size_t)b * FIN + (size_t)ch * 32 * 1024 + oy * 32 + ox;
    #pragma unroll
    for (int c = 0; c < 32; c++) {
        const float* wrc = wr + c * 27;
        float a = 0.f;
        #pragma unroll
        for (int k = 0; k < 27; k++) a = fmaf(xs[k], wrc[k], a);
        const int co = ch * 32 + c;
        float h = (a + s_bint[co]) * s_bsf[co];   // broadcast ds_read, conflict-free
        h = fmaxf(h, 0.f);
        mx = fmaxf(mx, h);
        outp[(size_t)c * 1024] = __half_as_ushort(__float2half(h));
    }
    float bm = blockMax(mx);
    if (t == 0) atomicMax(maxh, __float_as_uint(bm));
}

// ---- kernel 3: split-K f16 MFMA GEMM, reg-staged async double buffer ----
// grid: x = output tile (2x2 of 128x128), y = K slice (128 slices of 512)
// 512 blocks -> 2 blocks/CU. T14: issue next tile's global loads before the
// MFMA phase so HBM latency hides under compute + the co-resident block.
__global__ __launch_bounds__(256, 2) void k_gemm(const u16* __restrict__ h16,
                                                 const float* __restrict__ dw,
                                                 const float* __restrict__ ws,
                                                 float* __restrict__ accb) {
    __shared__ __align__(16) _Float16 As[128][72];
    __shared__ __align__(16) _Float16 Bs[128][72];
    __shared__ float invB[128];

    const int tid = threadIdx.x;
    const int tm  = (blockIdx.x >> 1) * 128;
    const int tn  = (blockIdx.x & 1) * 128;
    const int k0  = blockIdx.y * 512;

    const float max_h  = __uint_as_float(((const unsigned*)ws)[SC_F + 1]);
    const float p2     = fmaxf(max_h, 1e-8f) / 1023.0f;
    const float inv_p2 = 1.0f / p2;

    if (tid < 128) {
        const float* wp = ws + WPART_F + (size_t)(tn + tid) * 4;
        const float am = fmaxf(fmaxf(wp[0], wp[1]), fmaxf(wp[2], wp[3]));
        invB[tid] = 127.0f / fmaxf(am, 1e-8f);
    }

    floatx4 acc[4][4];
    const floatx4 zz = {0.f, 0.f, 0.f, 0.f};
    #pragma unroll
    for (int i = 0; i < 4; i++)
        #pragma unroll
        for (int j = 0; j < 4; j++) acc[i][j] = zz;

    const int wv = tid >> 6, lane = tid & 63;
    const int wm = (wv >> 1) * 64, wn = (wv & 1) * 64;
    const int lm = lane & 15, quad = lane >> 4;

    const int arow = tid >> 3, acol = tid & 7;    // A: 4 chunks/thread, rows +32
    const int brow = tid >> 4, bcol = tid & 15;   // B: 8 chunks/thread, rows +16

    half8  areg[4];
    float4 breg[8];

    // issue kk=0 loads immediately (before barrier; no LDS dependence)
    #pragma unroll
    for (int r = 0; r < 4; r++)
        areg[r] = *(const half8*)(h16 + (size_t)(tm + arow + r * 32) * FIN + k0 + acol * 8);
    #pragma unroll
    for (int r = 0; r < 8; r++)
        breg[r] = *(const float4*)(dw + (size_t)(tn + brow + r * 16) * FIN + k0 + bcol * 4);

    __syncthreads();   // invB ready

    for (int kk = 0; kk < 8; kk++) {
        // write-late: requantize staged regs into LDS
        #pragma unroll
        for (int r = 0; r < 4; r++) {
            half8 qv;
            #pragma unroll
            for (int j = 0; j < 8; j++) {
                float f = (float)areg[r][j];
                qv[j] = (_Float16)fminf(1023.f, rintf(f * inv_p2));
            }
            *(half8*)&As[arow + r * 32][acol * 8] = qv;
        }
        #pragma unroll
        for (int r = 0; r < 8; r++) {
            const float is = invB[brow + r * 16];
            float4 v = breg[r];
            half4v qv;
            qv[0] = (_Float16)fminf(127.f, fmaxf(-127.f, rintf(v.x * is)));
            qv[1] = (_Float16)fminf(127.f, fmaxf(-127.f, rintf(v.y * is)));
            qv[2] = (_Float16)fminf(127.f, fmaxf(-127.f, rintf(v.z * is)));
            qv[3] = (_Float16)fminf(127.f, fmaxf(-127.f, rintf(v.w * is)));
            *(half4v*)&Bs[brow + r * 16][bcol * 4] = qv;
        }
        __syncthreads();

        // issue-early: next tile's global loads fly during the MFMA phase
        if (kk < 7) {
            const int kn = k0 + (kk + 1) * 64;
            #pragma unroll
            for (int r = 0; r < 4; r++)
                areg[r] = *(const half8*)(h16 + (size_t)(tm + arow + r * 32) * FIN + kn + acol * 8);
            #pragma unroll
            for (int r = 0; r < 8; r++)
                breg[r] = *(const float4*)(dw + (size_t)(tn + brow + r * 16) * FIN + kn + bcol * 4);
        }

        #pragma unroll
        for (int ks = 0; ks < 2; ks++) {
            half8 af[4], bf[4];
            #pragma unroll
            for (int mi = 0; mi < 4; mi++)
                af[mi] = *(const half8*)&As[wm + mi * 16 + lm][ks * 32 + quad * 8];
            #pragma unroll
            for (int ni = 0; ni < 4; ni++)
                bf[ni] = *(const half8*)&Bs[wn + ni * 16 + lm][ks * 32 + quad * 8];
            #pragma unroll
            for (int mi = 0; mi < 4; mi++)
                #pragma unroll
                for (int ni = 0; ni < 4; ni++)
                    acc[mi][ni] = __builtin_amdgcn_mfma_f32_16x16x32_f16(af[mi], bf[ni], acc[mi][ni], 0, 0, 0);
        }
        __syncthreads();   // LDS consumed; safe to overwrite next iteration
    }

    #pragma unroll
    for (int mi = 0; mi < 4; mi++)
        #pragma unroll
        for (int ni = 0; ni < 4; ni++)
            #pragma unroll
            for (int r = 0; r < 4; r++) {
                const int row = tm + wm + mi * 16 + quad * 4 + r;
                const int col = tn + wn + ni * 16 + lm;
                atomicAdd(accb + row * FOUT + col, acc[mi][ni][r]);
            }
}

// ---- kernel 4: epilogue: +b_int, *bias_sf, relu ----
__global__ void k_epi(const float* __restrict__ accb, const float* __restrict__ db,
                      const float* __restrict__ ws, float* __restrict__ out) {
    const int idx = blockIdx.x * 256 + threadIdx.x;
    const int n = idx & 255;
    const float max_h = __uint_as_float(((const unsigned*)ws)[SC_F + 1]);
    const float p2 = fmaxf(max_h, 1e-8f) / 1023.0f;
    const float* wp = ws + WPART_F + (size_t)n * 4;
    const float am = fmaxf(fmaxf(fmaxf(wp[0], wp[1]), fmaxf(wp[2], wp[3])), 1e-8f);
    const float wsf = am / 127.0f;
    const float bsf = p2 * wsf;
    const float bint = rintf(db[n] / bsf);
    out[idx] = fmaxf(0.f, (accb[idx] + bint) * bsf);
}

extern "C" void kernel_launch(void* const* d_in, const int* in_sizes, int n_in,
                              void* d_out, int out_size, void* d_ws, size_t ws_size,
                              hipStream_t stream) {
    (void)in_sizes; (void)n_in; (void)out_size; (void)ws_size;
    const float* x  = (const float*)d_in[0];
    const float* cw = (const float*)d_in[1];
    const float* cb = (const float*)d_in[2];
    const float* dw = (const float*)d_in[3];
    const float* db = (const float*)d_in[4];
    float* out = (float*)d_out;
    float* ws  = (float*)d_ws;
    u16* h16   = (u16*)((char*)d_ws + H16_BYTE);
    float* accb = ws + ACC_F;
    unsigned* maxh = (unsigned*)ws + SC_F + 1;

    // 4 enqueues, no memset: stats -> conv -> gemm -> epilogue
    k_stats<<<1793, 256, 0, stream>>>(x, dw, cw, ws);
    k_conv<<<2048, 256, 0, stream>>>(x, cb, ws, h16, maxh);
    k_gemm<<<dim3(4, 128), 256, 0, stream>>>(h16, dw, ws, accb);
    k_epi<<<256, 256, 0, stream>>>(accb, db, ws, out);
}

// Round 5
// 198.008 us; speedup vs baseline: 1.2669x; 1.0903x over previous
//
#include <hip/hip_runtime.h>
#include <hip/hip_fp16.h>
#include <cstdint>

// Problem shape
#define B_   256
#define CIN  3
#define HW_  64
#define COUT 64
#define FIN  65536   // 64*32*32
#define FOUT 256

// Workspace layout (float indices)
#define ACC_F    0        // 65536: split-K GEMM accumulator (zeroed by k_stats)
#define SC_F     65536    // 16: [1] = max_h bits (atomicMax; zeroed by k_stats)
#define XPART_F  65552    // 512: per-block partial absmax of x (plain writes)
#define WPART_F  66064    // 1024: per-(row,quarter) partial absmax of dense_w
#define CSF_F    67088    // 64: conv per-channel weight scale
#define CWINT_F  67152    // 1728: conv w_int (float-valued, s_load path in k_conv)
#define H16_BYTE (512*1024)  // f16 h buffer, 33.5 MB

typedef _Float16 half8  __attribute__((ext_vector_type(8)));
typedef _Float16 half4v __attribute__((ext_vector_type(4)));
typedef float    floatx4 __attribute__((ext_vector_type(4)));
typedef unsigned short u16;

__device__ inline float blockMax(float v) {
    #pragma unroll
    for (int off = 32; off; off >>= 1) v = fmaxf(v, __shfl_down(v, off));
    __shared__ float sm[8];
    const int lane = threadIdx.x & 63, w = threadIdx.x >> 6;
    if (lane == 0) sm[w] = v;
    __syncthreads();
    float m = sm[0];
    const int nw = blockDim.x >> 6;
    for (int i = 1; i < nw; i++) m = fmaxf(m, sm[i]);
    return m;
}

// ---- kernel 1: all input statistics + conv weight quant + accb zero ----
__global__ __launch_bounds__(256) void k_stats(const float* __restrict__ x,
                                               const float* __restrict__ dw,
                                               const float* __restrict__ cw,
                                               float* __restrict__ ws) {
    const int b = blockIdx.x;
    const int t = threadIdx.x;
    if (b < 512) {
        const float4* x4 = (const float4*)x;
        float m = 0.f;
        for (int i = b * 256 + t; i < (B_ * CIN * HW_ * HW_) / 4; i += 512 * 256) {
            float4 v = x4[i];
            m = fmaxf(m, fmaxf(fmaxf(fabsf(v.x), fabsf(v.y)), fmaxf(fabsf(v.z), fabsf(v.w))));
        }
        float bm = blockMax(m);
        if (t == 0) ws[XPART_F + b] = bm;
    } else if (b < 1536) {
        const int b2 = b - 512;
        const int row = b2 >> 2, q = b2 & 3;
        const float4* r = (const float4*)(dw + (size_t)row * FIN) + q * 4096;
        float m = 0.f;
        for (int i = t; i < 4096; i += 256) {
            float4 v = r[i];
            m = fmaxf(m, fmaxf(fmaxf(fabsf(v.x), fabsf(v.y)), fmaxf(fabsf(v.z), fabsf(v.w))));
        }
        float bm = blockMax(m);
        if (t == 0) ws[WPART_F + b2] = bm;
    } else if (b == 1536) {
        if (t == 64) ((unsigned*)ws)[SC_F + 1] = 0u;   // zero max_h slot for k_conv's atomicMax
        if (t < 64) {
            const int o = t;
            float wv[27];
            float m = 0.f;
            #pragma unroll
            for (int i = 0; i < 27; i++) { wv[i] = cw[o * 27 + i]; m = fmaxf(m, fabsf(wv[i])); }
            const float sf = fmaxf(m, 1e-8f) / 127.0f;
            #pragma unroll
            for (int i = 0; i < 27; i++)
                ws[CWINT_F + o * 27 + i] = fminf(127.f, fmaxf(-127.f, rintf(wv[i] / sf)));
            ws[CSF_F + o] = sf;
        }
    } else {
        // zero GEMM accumulator (visible to k_gemm at kernel boundary)
        ws[ACC_F + (b - 1537) * 256 + t] = 0.f;
    }
}

// ---- kernel 2: conv 3x3 s2 p1, relu, f16 store, global max(h) ----
// r4 post-mortem: the 76% stall was SMEM latency (per-channel weight s_loads,
// burst-limited by SGPR budget) + xs bouncing off-VGPR. Fix both:
//  (a) xs: gather each thread's 27 window values into a CONTIGUOUS per-thread
//      LDS slab, read back as 7 x b128, pin the 7 vectors with ONE asm ->
//      28 VGPRs, no remat, low pressure.
//  (b) weights: explicit double-buffer -- load channel c+1's weights (uniform
//      -> SGPR) before channel c's fma run, so s_load latency overlaps fma.
// ws stays CONST+RESTRICT (r2 lesson: writable ws kills the s_load path).
__global__ __launch_bounds__(256) void k_conv(const float* __restrict__ x,
                                              const float* __restrict__ cb,
                                              const float* __restrict__ ws,
                                              u16* __restrict__ h16,
                                              unsigned* __restrict__ maxh) {
    __shared__ float s_bsf[64], s_bint[64];
    __shared__ float xt[27 * 68];     // staged+requantized input, halo cols
    __shared__ float xp[256 * 28];    // per-thread contiguous window (16B-aligned stride)
    const int t = threadIdx.x;

    // p_sf from the 512 x-partials (blockMax contains the needed syncthreads)
    float pm = fmaxf(ws[XPART_F + t], ws[XPART_F + 256 + t]);
    pm = blockMax(pm);
    const float p_sf = fmaxf(pm, 1e-8f) / 32767.0f;
    const float inv_p = 1.0f / p_sf;
    if (t < 64) {
        const float bsf = p_sf * ws[CSF_F + t];
        s_bsf[t]  = bsf;
        s_bint[t] = rintf(cb[t] / bsf);
    }

    const int b   = blockIdx.x >> 3;
    const int oyt = (blockIdx.x & 7) * 4;
    const float* xb = x + (size_t)b * (CIN * HW_ * HW_);

    // stage 27 rows x 64 cols, requantized; 432 float4 chunks over 256 threads
    for (int i = t; i < 432; i += 256) {
        const int lrow = i >> 4, c4 = i & 15;
        const int ci = lrow / 9, lr = lrow - ci * 9;
        const int iy = 2 * oyt - 1 + lr;
        float4 v = make_float4(0.f, 0.f, 0.f, 0.f);
        if ((unsigned)iy < 64u) v = *(const float4*)(xb + (ci * HW_ + iy) * HW_ + c4 * 4);
        float* d = &xt[lrow * 68 + 1 + c4 * 4];
        d[0] = fminf(32767.f, fmaxf(-32767.f, rintf(v.x * inv_p)));
        d[1] = fminf(32767.f, fmaxf(-32767.f, rintf(v.y * inv_p)));
        d[2] = fminf(32767.f, fmaxf(-32767.f, rintf(v.z * inv_p)));
        d[3] = fminf(32767.f, fmaxf(-32767.f, rintf(v.w * inv_p)));
    }
    if (t < 27) xt[t * 68] = 0.f;                      // ix = -1 halo
    else if (t < 54) xt[(t - 27) * 68 + 65] = 0.f;     // ix = 64 halo
    __syncthreads();

    const int ox = t & 31;
    const int ch = __builtin_amdgcn_readfirstlane((t >> 6) & 1);  // wave-uniform
    const int dy = ((t >> 7) << 1) + ((t >> 5) & 1);              // 0..3
    const int oy = oyt + dy;

    // gather own window into contiguous slab (once; 2-way strided reads are free)
    float* myp = &xp[t * 28];
    #pragma unroll
    for (int ci = 0; ci < 3; ci++)
        #pragma unroll
        for (int ky = 0; ky < 3; ky++) {
            const float* rowp = &xt[(ci * 9 + 2 * dy + ky) * 68 + 2 * ox];
            #pragma unroll
            for (int kx = 0; kx < 3; kx++)
                myp[ci * 9 + ky * 3 + kx] = rowp[kx];
        }
    // read back as 7 x b128 and pin the vectors: 28 VGPRs, remat impossible
    floatx4 xv0 = *(const floatx4*)(myp + 0);
    floatx4 xv1 = *(const floatx4*)(myp + 4);
    floatx4 xv2 = *(const floatx4*)(myp + 8);
    floatx4 xv3 = *(const floatx4*)(myp + 12);
    floatx4 xv4 = *(const floatx4*)(myp + 16);
    floatx4 xv5 = *(const floatx4*)(myp + 20);
    floatx4 xv6 = *(const floatx4*)(myp + 24);
    asm volatile("" : "+v"(xv0), "+v"(xv1), "+v"(xv2), "+v"(xv3),
                      "+v"(xv4), "+v"(xv5), "+v"(xv6));
    float xs[27];
    #pragma unroll
    for (int k = 0; k < 27; k++) {
        const int q = k >> 2, r = k & 3;
        xs[k] = (q == 0) ? xv0[r] : (q == 1) ? xv1[r] : (q == 2) ? xv2[r] :
                (q == 3) ? xv3[r] : (q == 4) ? xv4[r] : (q == 5) ? xv5[r] : xv6[r];
    }

    const float* wr = ws + CWINT_F + ch * (32 * 27);  // uniform + const -> s_load
    float mx = 0.f;
    u16* outp = h16 + (size_t)b * FIN + (size_t)ch * 32 * 1024 + oy * 32 + ox;

    // weight double-buffer: wnext loads (SGPR, uniform) overlap current fmas
    float wbuf[27];
    #pragma unroll
    for (int k = 0; k < 27; k++) wbuf[k] = wr[k];
    #pragma unroll
    for (int c = 0; c < 32; c++) {
        float wcur[27];
        #pragma unroll
        for (int k = 0; k < 27; k++) wcur[k] = wbuf[k];
        if (c < 31) {
            const float* wn = wr + (c + 1) * 27;
            #pragma unroll
            for (int k = 0; k < 27; k++) wbuf[k] = wn[k];
        }
        float a = 0.f;
        #pragma unroll
        for (int k = 0; k < 27; k++) a = fmaf(xs[k], wcur[k], a);
        const int co = ch * 32 + c;
        float h = (a + s_bint[co]) * s_bsf[co];   // broadcast ds_read, conflict-free
        h = fmaxf(h, 0.f);
        mx = fmaxf(mx, h);
        outp[(size_t)c * 1024] = __half_as_ushort(__float2half(h));
    }
    float bm = blockMax(mx);
    if (t == 0) atomicMax(maxh, __float_as_uint(bm));
}

// ---- kernel 3: split-K f16 MFMA GEMM, reg-staged async double buffer ----
// grid: x = output tile (2x2 of 128x128), y = K slice (128 slices of 512)
// 512 blocks -> 2 blocks/CU. T14: issue next tile's global loads before the
// MFMA phase so HBM latency hides under compute + the co-resident block.
__global__ __launch_bounds__(256, 2) void k_gemm(const u16* __restrict__ h16,
                                                 const float* __restrict__ dw,
                                                 const float* __restrict__ ws,
                                                 float* __restrict__ accb) {
    __shared__ __align__(16) _Float16 As[128][72];
    __shared__ __align__(16) _Float16 Bs[128][72];
    __shared__ float invB[128];

    const int tid = threadIdx.x;
    const int tm  = (blockIdx.x >> 1) * 128;
    const int tn  = (blockIdx.x & 1) * 128;
    const int k0  = blockIdx.y * 512;

    const float max_h  = __uint_as_float(((const unsigned*)ws)[SC_F + 1]);
    const float p2     = fmaxf(max_h, 1e-8f) / 1023.0f;
    const float inv_p2 = 1.0f / p2;

    if (tid < 128) {
        const float* wp = ws + WPART_F + (size_t)(tn + tid) * 4;
        const float am = fmaxf(fmaxf(wp[0], wp[1]), fmaxf(wp[2], wp[3]));
        invB[tid] = 127.0f / fmaxf(am, 1e-8f);
    }

    floatx4 acc[4][4];
    const floatx4 zz = {0.f, 0.f, 0.f, 0.f};
    #pragma unroll
    for (int i = 0; i < 4; i++)
        #pragma unroll
        for (int j = 0; j < 4; j++) acc[i][j] = zz;

    const int wv = tid >> 6, lane = tid & 63;
    const int wm = (wv >> 1) * 64, wn = (wv & 1) * 64;
    const int lm = lane & 15, quad = lane >> 4;

    const int arow = tid >> 3, acol = tid & 7;    // A: 4 chunks/thread, rows +32
    const int brow = tid >> 4, bcol = tid & 15;   // B: 8 chunks/thread, rows +16

    half8  areg[4];
    float4 breg[8];

    // issue kk=0 loads immediately (before barrier; no LDS dependence)
    #pragma unroll
    for (int r = 0; r < 4; r++)
        areg[r] = *(const half8*)(h16 + (size_t)(tm + arow + r * 32) * FIN + k0 + acol * 8);
    #pragma unroll
    for (int r = 0; r < 8; r++)
        breg[r] = *(const float4*)(dw + (size_t)(tn + brow + r * 16) * FIN + k0 + bcol * 4);

    __syncthreads();   // invB ready

    for (int kk = 0; kk < 8; kk++) {
        // write-late: requantize staged regs into LDS
        #pragma unroll
        for (int r = 0; r < 4; r++) {
            half8 qv;
            #pragma unroll
            for (int j = 0; j < 8; j++) {
                float f = (float)areg[r][j];
                qv[j] = (_Float16)fminf(1023.f, rintf(f * inv_p2));
            }
            *(half8*)&As[arow + r * 32][acol * 8] = qv;
        }
        #pragma unroll
        for (int r = 0; r < 8; r++) {
            const float is = invB[brow + r * 16];
            float4 v = breg[r];
            half4v qv;
            qv[0] = (_Float16)fminf(127.f, fmaxf(-127.f, rintf(v.x * is)));
            qv[1] = (_Float16)fminf(127.f, fmaxf(-127.f, rintf(v.y * is)));
            qv[2] = (_Float16)fminf(127.f, fmaxf(-127.f, rintf(v.z * is)));
            qv[3] = (_Float16)fminf(127.f, fmaxf(-127.f, rintf(v.w * is)));
            *(half4v*)&Bs[brow + r * 16][bcol * 4] = qv;
        }
        __syncthreads();

        // issue-early: next tile's global loads fly during the MFMA phase
        if (kk < 7) {
            const int kn = k0 + (kk + 1) * 64;
            #pragma unroll
            for (int r = 0; r < 4; r++)
                areg[r] = *(const half8*)(h16 + (size_t)(tm + arow + r * 32) * FIN + kn + acol * 8);
            #pragma unroll
            for (int r = 0; r < 8; r++)
                breg[r] = *(const float4*)(dw + (size_t)(tn + brow + r * 16) * FIN + kn + bcol * 4);
        }

        #pragma unroll
        for (int ks = 0; ks < 2; ks++) {
            half8 af[4], bf[4];
            #pragma unroll
            for (int mi = 0; mi < 4; mi++)
                af[mi] = *(const half8*)&As[wm + mi * 16 + lm][ks * 32 + quad * 8];
            #pragma unroll
            for (int ni = 0; ni < 4; ni++)
                bf[ni] = *(const half8*)&Bs[wn + ni * 16 + lm][ks * 32 + quad * 8];
            #pragma unroll
            for (int mi = 0; mi < 4; mi++)
                #pragma unroll
                for (int ni = 0; ni < 4; ni++)
                    acc[mi][ni] = __builtin_amdgcn_mfma_f32_16x16x32_f16(af[mi], bf[ni], acc[mi][ni], 0, 0, 0);
        }
        __syncthreads();   // LDS consumed; safe to overwrite next iteration
    }

    #pragma unroll
    for (int mi = 0; mi < 4; mi++)
        #pragma unroll
        for (int ni = 0; ni < 4; ni++)
            #pragma unroll
            for (int r = 0; r < 4; r++) {
                const int row = tm + wm + mi * 16 + quad * 4 + r;
                const int col = tn + wn + ni * 16 + lm;
                atomicAdd(accb + row * FOUT + col, acc[mi][ni][r]);
            }
}

// ---- kernel 4: epilogue: +b_int, *bias_sf, relu ----
__global__ void k_epi(const float* __restrict__ accb, const float* __restrict__ db,
                      const float* __restrict__ ws, float* __restrict__ out) {
    const int idx = blockIdx.x * 256 + threadIdx.x;
    const int n = idx & 255;
    const float max_h = __uint_as_float(((const unsigned*)ws)[SC_F + 1]);
    const float p2 = fmaxf(max_h, 1e-8f) / 1023.0f;
    const float* wp = ws + WPART_F + (size_t)n * 4;
    const float am = fmaxf(fmaxf(fmaxf(wp[0], wp[1]), fmaxf(wp[2], wp[3])), 1e-8f);
    const float wsf = am / 127.0f;
    const float bsf = p2 * wsf;
    const float bint = rintf(db[n] / bsf);
    out[idx] = fmaxf(0.f, (accb[idx] + bint) * bsf);
}

extern "C" void kernel_launch(void* const* d_in, const int* in_sizes, int n_in,
                              void* d_out, int out_size, void* d_ws, size_t ws_size,
                              hipStream_t stream) {
    (void)in_sizes; (void)n_in; (void)out_size; (void)ws_size;
    const float* x  = (const float*)d_in[0];
    const float* cw = (const float*)d_in[1];
    const float* cb = (const float*)d_in[2];
    const float* dw = (const float*)d_in[3];
    const float* db = (const float*)d_in[4];
    float* out = (float*)d_out;
    float* ws  = (float*)d_ws;
    u16* h16   = (u16*)((char*)d_ws + H16_BYTE);
    float* accb = ws + ACC_F;
    unsigned* maxh = (unsigned*)ws + SC_F + 1;

    // 4 enqueues, no memset: stats -> conv -> gemm -> epilogue
    k_stats<<<1793, 256, 0, stream>>>(x, dw, cw, ws);
    k_conv<<<2048, 256, 0, stream>>>(x, cb, ws, h16, maxh);
    k_gemm<<<dim3(4, 128), 256, 0, stream>>>(h16, dw, ws, accb);
    k_epi<<<256, 256, 0, stream>>>(accb, db, ws, out);
}